// Round 18
// baseline (108.255 us; speedup 1.0000x reference)
//
#include <hip/hip_runtime.h>

typedef __attribute__((ext_vector_type(8))) __bf16 bf16x8;
typedef __attribute__((ext_vector_type(4))) float  f32x4;
typedef unsigned short u16;
typedef unsigned int   u32;

// ---------- helpers ----------
__device__ __forceinline__ u16 f2b(float f) {           // f32 -> bf16 (RNE)
  u32 u = __builtin_bit_cast(u32, f);
  u32 r = (u + 0x7FFFu + ((u >> 16) & 1u)) >> 16;
  return (u16)r;
}

typedef __attribute__((address_space(3))) void lds_void;
typedef const __attribute__((address_space(1))) void gbl_void;

__device__ __forceinline__ void gload_lds16(const u16* g, u16* l) {
  __builtin_amdgcn_global_load_lds((gbl_void*)g, (lds_void*)l, 16, 0, 0);
}

#define QSCALE 0.18033688011112042f  /* log2(e)/8 : exp2-domain score scale */
#define MFIX   4.328085122666891f    /* 3*log2(e) : fixed softmax max (exp2 dom) */

// ---------- fused prep: x cast + weight transposes (one launch) ----------
__global__ __launch_bounds__(256) void prep_all(const float* __restrict__ x,
                                                const float* __restrict__ wq,
                                                const float* __restrict__ wk,
                                                const float* __restrict__ wv,
                                                const float* __restrict__ wo,
                                                u16* __restrict__ xb,
                                                u16* __restrict__ wbt,
                                                u16* __restrict__ wot) {
  int bid = blockIdx.x;
  int tid = threadIdx.x;
  if (bid < 4096) {
    int i = bid * 256 + tid;
    float4 v = ((const float4*)x)[i];
    ushort4 o;
    o.x = f2b(v.x); o.y = f2b(v.y); o.z = f2b(v.z); o.w = f2b(v.w);
    ((ushort4*)xb)[i] = o;
    return;
  }
  __shared__ float t[64][65];
  int sub = bid - 4096;
  const float* src; u16* dst; int sstride, dstride, r0, c0;
  if (sub < 768) {
    int proj = sub >> 8, rem = sub & 255;
    int ym = rem >> 4, xt = rem & 15;
    src = ((proj == 0) ? wq : (proj == 1) ? wk : wv) + (size_t)ym * 65536;
    dst = wbt + ((size_t)proj << 20) + (size_t)ym * 65536;
    sstride = 64; dstride = 1024; r0 = xt * 64; c0 = 0;
  } else {
    int s2 = sub - 768;
    src = wo; dst = wot;
    sstride = 1024; dstride = 1024;
    r0 = (s2 & 15) * 64; c0 = (s2 >> 4) * 64;
  }
  int rr = tid >> 2, q = tid & 3;
#pragma unroll
  for (int i = 0; i < 4; ++i) {
    float4 v = *(const float4*)&src[(size_t)(r0 + rr) * sstride + c0 + q * 16 + i * 4];
    t[rr][q * 16 + i * 4 + 0] = v.x;
    t[rr][q * 16 + i * 4 + 1] = v.y;
    t[rr][q * 16 + i * 4 + 2] = v.z;
    t[rr][q * 16 + i * 4 + 3] = v.w;
  }
  __syncthreads();
  int cc = rr;
#pragma unroll
  for (int i = 0; i < 4; ++i) {
    ushort4 o;
    o.x = f2b(t[q * 16 + i * 4 + 0][cc]);
    o.y = f2b(t[q * 16 + i * 4 + 1][cc]);
    o.z = f2b(t[q * 16 + i * 4 + 2][cc]);
    o.w = f2b(t[q * 16 + i * 4 + 3][cc]);
    *(ushort4*)&dst[(size_t)(c0 + cc) * dstride + r0 + q * 16 + i * 4] = o;
  }
}

// ---------- shared GEMM mainloop: 128x128 tile, BK=32, 4 waves (r4/r7 form) ----------
template <int KDIM>
__device__ __forceinline__ void gemm_main(const u16* __restrict__ A,
                                          const u16* __restrict__ Bm,
                                          int R0, int C0,
                                          u16* As, u16* Bs, f32x4 (&acc)[4][4]) {
  int tid = threadIdx.x;
  int w = tid >> 6, l = tid & 63;
  int lr = l & 15, lg = l >> 4;
  int wr = w >> 1, wc = w & 1;
  for (int k0 = 0; k0 < KDIM; k0 += 32) {
#pragma unroll
    for (int i = 0; i < 2; ++i) {
      int t = w * 2 + i;
      gload_lds16(A  + (size_t)(R0 + t * 16 + (l >> 2)) * KDIM + k0 + (l & 3) * 8, &As[t * 512]);
      gload_lds16(Bm + (size_t)(C0 + t * 16 + (l >> 2)) * KDIM + k0 + (l & 3) * 8, &Bs[t * 512]);
    }
    __syncthreads();
    bf16x8 af[4], bfr[4];
#pragma unroll
    for (int mi = 0; mi < 4; ++mi)
      af[mi] = *(const bf16x8*)&As[(wr * 64 + mi * 16 + lr) * 32 + lg * 8];
#pragma unroll
    for (int ni = 0; ni < 4; ++ni)
      bfr[ni] = *(const bf16x8*)&Bs[(wc * 64 + ni * 16 + lr) * 32 + lg * 8];
#pragma unroll
    for (int mi = 0; mi < 4; ++mi)
#pragma unroll
      for (int ni = 0; ni < 4; ++ni)
        acc[mi][ni] = __builtin_amdgcn_mfma_f32_16x16x32_bf16(af[mi], bfr[ni], acc[mi][ni], 0, 0, 0);
    __syncthreads();
  }
}

// ---------- GEMM1: Y = x @ [Wq|Wk|Wv] ; 128x128, grid 768, direct scatter (r7/r8) ----------
__global__ __launch_bounds__(256) void gemm_qkv(const u16* __restrict__ xb,
                                                const u16* __restrict__ wbt,
                                                const float* __restrict__ bq,
                                                const float* __restrict__ bk,
                                                const float* __restrict__ bv,
                                                u16* __restrict__ qb,
                                                u16* __restrict__ kbf,
                                                u16* __restrict__ vtb) {
  __shared__ __align__(16) u16 As[128 * 32];
  __shared__ __align__(16) u16 Bs[128 * 32];
  f32x4 acc[4][4];
#pragma unroll
  for (int mi = 0; mi < 4; ++mi)
#pragma unroll
    for (int ni = 0; ni < 4; ++ni) acc[mi][ni] = (f32x4){0.f, 0.f, 0.f, 0.f};

  int bid = blockIdx.x;
  int rt = bid & 31, ct = bid >> 5;   // 32 row tiles x 24 col tiles
  int R0 = rt * 128, C0 = ct * 128;
  gemm_main<1024>(xb, wbt, R0, C0, As, Bs, acc);

  int tid = threadIdx.x;
  int w = tid >> 6, l = tid & 63;
  int lr = l & 15, lg = l >> 4;
  int wr = w >> 1, wc = w & 1;
#pragma unroll
  for (int ni = 0; ni < 4; ++ni) {
    int col = C0 + wc * 64 + ni * 16 + lr;
    int proj = col >> 10;            // uniform per block
    int within = col & 1023;
    int n = within >> 6, h = within & 63;
    const float* bias = (proj == 0) ? bq : (proj == 1 ? bk : bv);
    float badd = bias[within];
    float scl = (proj == 0) ? QSCALE : 1.0f;   // fold score scale+log2e into Q
#pragma unroll
    for (int mi = 0; mi < 4; ++mi) {
#pragma unroll
      for (int r = 0; r < 4; ++r) {
        int row = R0 + wr * 64 + mi * 16 + lg * 4 + r;
        int b = row >> 11, p = row & 2047;
        int bn = b * 16 + n;
        u16 u = f2b((acc[mi][ni][r] + badd) * scl);
        if (proj == 0)      qb [((size_t)bn * 2048 + p) * 64 + h] = u;
        else if (proj == 1) kbf[((size_t)bn * 2048 + p) * 64 + h] = u;
        else                vtb[(((size_t)bn * 32 + (p >> 6)) * 64 + h) * 64 + (p & 63)] = u;
      }
    }
  }
}

// ---------- flash attention (inverted-causal mask: keep pk > pq) ----------
// 1056 blocks: 0..1023 = (32 bn x 32 chunks, LPT); 1024..1055 = fused mean_v
// (row-2047 output: uniform softmax -> mean(V); attn path skips that row).
// 4 waves/block; LDS 40KB -> 4 blocks/CU. 2-buffer K/V staging, depth-1
// prefetch with counted vmcnt(4), raw barriers. Fixed-max softmax (exp2).
#define ATTN_STEP(BUFC, MASKED)                                                \
  {                                                                            \
    if (t + 1 < trips) {                                                       \
      gload_lds16(sk,       &Ks[BUFC ^ 1][w * 1024]);                          \
      gload_lds16(sk + 512, &Ks[BUFC ^ 1][w * 1024 + 512]);                    \
      gload_lds16(sv,       &Vs[BUFC ^ 1][w * 1024]);                          \
      gload_lds16(sv + 512, &Vs[BUFC ^ 1][w * 1024 + 512]);                    \
      sk += 4096; sv += 4096;                                                  \
      asm volatile("s_waitcnt vmcnt(4)" ::: "memory");                         \
    } else {                                                                   \
      asm volatile("s_waitcnt vmcnt(0)" ::: "memory");                         \
    }                                                                          \
    __builtin_amdgcn_s_barrier();                                              \
    asm volatile("" ::: "memory");                                             \
    f32x4 sacc[4];                                                             \
    __builtin_amdgcn_s_setprio(1);                                             \
    _Pragma("unroll") for (int nb = 0; nb < 4; ++nb) {                         \
      int row = nb * 16 + lr, sw = row & 7;                                    \
      bf16x8 kf0 = *(const bf16x8*)&Ks[BUFC][row * 64 + ((lg ^ sw) << 3)];     \
      bf16x8 kf1 = *(const bf16x8*)&Ks[BUFC][row * 64 + (((lg + 4) ^ sw) << 3)]; \
      f32x4 s = (f32x4){0.f, 0.f, 0.f, 0.f};                                   \
      s = __builtin_amdgcn_mfma_f32_16x16x32_bf16(qf0, kf0, s, 0, 0, 0);       \
      s = __builtin_amdgcn_mfma_f32_16x16x32_bf16(qf1, kf1, s, 0, 0, 0);       \
      sacc[nb] = s;                                                            \
    }                                                                          \
    __builtin_amdgcn_s_setprio(0);                                             \
    u16 pbv[4][4];                                                             \
    if (MASKED) {                                                              \
      _Pragma("unroll") for (int nb = 0; nb < 4; ++nb) {                       \
        int key = nb * 16 + lr;                                                \
        _Pragma("unroll") for (int r = 0; r < 4; ++r) {                        \
          int qrow = w * 16 + lg * 4 + r;                                      \
          float xv = (key > qrow) ? sacc[nb][r] : -1.0e10f;                    \
          float pe = __builtin_amdgcn_exp2f(xv - MFIX);                        \
          rsum[r] += pe;                                                       \
          pbv[nb][r] = __builtin_bit_cast(u16, (__bf16)pe);                    \
        }                                                                      \
      }                                                                        \
    } else {                                                                   \
      _Pragma("unroll") for (int nb = 0; nb < 4; ++nb)                         \
        _Pragma("unroll") for (int r = 0; r < 4; ++r) {                        \
          float pe = __builtin_amdgcn_exp2f(sacc[nb][r] - MFIX);               \
          rsum[r] += pe;                                                       \
          pbv[nb][r] = __builtin_bit_cast(u16, (__bf16)pe);                    \
        }                                                                      \
    }                                                                          \
    _Pragma("unroll") for (int nb = 0; nb < 4; ++nb)                           \
      _Pragma("unroll") for (int r = 0; r < 4; ++r) {                          \
        int prow = lg * 4 + r;                                                 \
        Plds[w][prow * 64 + ((((nb * 2) + (lr >> 3)) ^ (prow & 7)) << 3) + (lr & 7)] = pbv[nb][r]; \
      }                                                                        \
    asm volatile("s_waitcnt lgkmcnt(0)" ::: "memory");                         \
    __builtin_amdgcn_sched_barrier(0);                                         \
    bf16x8 pf0 = *(const bf16x8*)&Plds[w][lr * 64 + ((lg ^ (lr & 7)) << 3)];   \
    bf16x8 pf1 = *(const bf16x8*)&Plds[w][lr * 64 + (((4 + lg) ^ (lr & 7)) << 3)]; \
    __builtin_amdgcn_s_setprio(1);                                             \
    _Pragma("unroll") for (int hb = 0; hb < 4; ++hb) {                         \
      int row = hb * 16 + lr, sw = row & 7;                                    \
      bf16x8 vf0 = *(const bf16x8*)&Vs[BUFC][row * 64 + ((lg ^ sw) << 3)];     \
      bf16x8 vf1 = *(const bf16x8*)&Vs[BUFC][row * 64 + (((lg + 4) ^ sw) << 3)]; \
      oacc[hb] = __builtin_amdgcn_mfma_f32_16x16x32_bf16(pf0, vf0, oacc[hb], 0, 0, 0); \
      oacc[hb] = __builtin_amdgcn_mfma_f32_16x16x32_bf16(pf1, vf1, oacc[hb], 0, 0, 0); \
    }                                                                          \
    __builtin_amdgcn_s_setprio(0);                                             \
    asm volatile("" ::: "memory");                                             \
    __builtin_amdgcn_s_barrier();                                              \
    ++t;                                                                       \
  }

__global__ __launch_bounds__(256, 4) void attn_kern(const u16* __restrict__ qb,
                                                    const u16* __restrict__ kbf,
                                                    const u16* __restrict__ vtb,
                                                    u16* __restrict__ zb) {
  __shared__ __align__(16) u16 Ks[2][4096];   // 16 KB
  __shared__ __align__(16) u16 Vs[2][4096];   // 16 KB
  __shared__ __align__(16) u16 Plds[4][1024]; // 8 KB, XOR-swizzled [16][64]/wave

  int bid = blockIdx.x;
  int tid = threadIdx.x;

  if (bid >= 1024) {
    // ---- fused mean_v: row-2047 output = mean over V rows (uniform softmax) ----
    float* red = (float*)&Ks[0][0];          // alias 1 KB of the staging pool
    int bn = bid - 1024;
    int w = tid >> 6, h = tid & 63;
    const u16* base = vtb + (size_t)bn * 131072 + (size_t)h * 64;
    float acc = 0.f;
    for (int pb = w; pb < 32; pb += 4) {
      const u16* r = base + (size_t)pb * 4096;
#pragma unroll
      for (int c = 0; c < 8; ++c) {
        bf16x8 v = *(const bf16x8*)(r + c * 8);
#pragma unroll
        for (int j = 0; j < 8; ++j) acc += (float)v[j];
      }
    }
    red[w * 64 + h] = acc;
    __syncthreads();
    if (w == 0) {
      float s = (red[h] + red[64 + h] + red[128 + h] + red[192 + h]) * (1.0f / 2048.0f);
      int b = bn >> 4, n = bn & 15;
      zb[((size_t)(b * 2048 + 2047) * 16 + n) * 64 + h] = f2b(s);
    }
    return;
  }

  int bn = bid & 31, c = bid >> 5;        // c ascending = longest-first (LPT)
  int trips = 32 - c;                     // k-tiles c..31
  int w = tid >> 6, l = tid & 63;
  int lr = l & 15, lg = l >> 4;

  const u16* Q  = qb  + (size_t)bn * 131072;
  const u16* Kp = kbf + (size_t)bn * 131072;
  const u16* Vt = vtb + (size_t)bn * 131072;

  // staging source offset with inverse XOR-swizzle (LDS dest stays linear)
  int row0 = w * 16 + (l >> 3), col8 = l & 7;
  int soff = row0 * 64 + ((col8 ^ (row0 & 7)) << 3);

  int q0w = c * 64 + w * 16;
  bf16x8 qf0 = *(const bf16x8*)&Q[(size_t)(q0w + lr) * 64 + lg * 8];
  bf16x8 qf1 = *(const bf16x8*)&Q[(size_t)(q0w + lr) * 64 + 32 + lg * 8];

  float rsum[4];
  f32x4 oacc[4];
#pragma unroll
  for (int r = 0; r < 4; ++r) rsum[r] = 0.0f;
#pragma unroll
  for (int hb = 0; hb < 4; ++hb) oacc[hb] = (f32x4){0.f, 0.f, 0.f, 0.f};

  // prologue: stage tile 0 into buf 0
  const u16* sk = Kp + (size_t)c * 4096 + soff;
  const u16* sv = Vt + (size_t)c * 4096 + soff;
  gload_lds16(sk,       &Ks[0][w * 1024]);
  gload_lds16(sk + 512, &Ks[0][w * 1024 + 512]);
  gload_lds16(sv,       &Vs[0][w * 1024]);
  gload_lds16(sv + 512, &Vs[0][w * 1024 + 512]);
  sk += 4096; sv += 4096;

  int t = 0;
  ATTN_STEP(0, true)                       // t=0: masked tile
  while (t + 1 < trips) {
    ATTN_STEP(1, false)
    ATTN_STEP(0, false)
  }
  if (t < trips) ATTN_STEP(1, false)       // tail (trips even)

  // ---- final row-sum reduce + store (skip row 2047: owned by mean_v blocks) ----
#pragma unroll
  for (int r = 0; r < 4; ++r) {
    float v = rsum[r];
    v += __shfl_xor(v, 1);
    v += __shfl_xor(v, 2);
    v += __shfl_xor(v, 4);
    v += __shfl_xor(v, 8);
    rsum[r] = 1.0f / v;
  }
  int b = bn >> 4, n = bn & 15;
#pragma unroll
  for (int hb = 0; hb < 4; ++hb) {
    int h = hb * 16 + lr;
#pragma unroll
    for (int r = 0; r < 4; ++r) {
      int qrow = q0w + lg * 4 + r;
      if (qrow != 2047)
        zb[((size_t)(b * 2048 + qrow) * 16 + n) * 64 + h] = f2b(oacc[hb][r] * rsum[r]);
    }
  }
}

// ---------- GEMM2: out = z @ Wo + bias_out (f32 out) ----------
// 128x64 tiles -> 512 blocks (2/CU); default dispatch order (swizzle removed:
// consecutive bids share the A-panel, same lesson as r11's gemm_qkv regression).
__global__ __launch_bounds__(256) void gemm_out(const u16* __restrict__ zb,
                                                const u16* __restrict__ wot,
                                                const float* __restrict__ bo,
                                                float* __restrict__ out) {
  __shared__ __align__(16) u16 As[128 * 32];  // 8 KB
  __shared__ __align__(16) u16 Bs[64 * 32];   // 4 KB
  f32x4 acc[4][2];
#pragma unroll
  for (int mi = 0; mi < 4; ++mi)
#pragma unroll
    for (int ni = 0; ni < 2; ++ni) acc[mi][ni] = (f32x4){0.f, 0.f, 0.f, 0.f};

  int bid = blockIdx.x;
  int rt = bid >> 4, ct = bid & 15;   // 32 row tiles x 16 col tiles
  int R0 = rt * 128, C0 = ct * 64;

  int tid = threadIdx.x;
  int w = tid >> 6, l = tid & 63;
  int lr = l & 15, lg = l >> 4;
  int wr = w >> 1, wc = w & 1;

  for (int k0 = 0; k0 < 1024; k0 += 32) {
#pragma unroll
    for (int i = 0; i < 2; ++i) {
      int t = w * 2 + i;
      gload_lds16(zb + (size_t)(R0 + t * 16 + (l >> 2)) * 1024 + k0 + (l & 3) * 8, &As[t * 512]);
    }
    gload_lds16(wot + (size_t)(C0 + w * 16 + (l >> 2)) * 1024 + k0 + (l & 3) * 8, &Bs[w * 512]);
    __syncthreads();
    bf16x8 af[4], bfr[2];
#pragma unroll
    for (int mi = 0; mi < 4; ++mi)
      af[mi] = *(const bf16x8*)&As[(wr * 64 + mi * 16 + lr) * 32 + lg * 8];
#pragma unroll
    for (int ni = 0; ni < 2; ++ni)
      bfr[ni] = *(const bf16x8*)&Bs[(wc * 32 + ni * 16 + lr) * 32 + lg * 8];
#pragma unroll
    for (int mi = 0; mi < 4; ++mi)
#pragma unroll
      for (int ni = 0; ni < 2; ++ni)
        acc[mi][ni] = __builtin_amdgcn_mfma_f32_16x16x32_bf16(af[mi], bfr[ni], acc[mi][ni], 0, 0, 0);
    __syncthreads();
  }

#pragma unroll
  for (int ni = 0; ni < 2; ++ni) {
    int col = C0 + wc * 32 + ni * 16 + lr;
    float badd = bo[col];
#pragma unroll
    for (int mi = 0; mi < 4; ++mi) {
#pragma unroll
      for (int r = 0; r < 4; ++r) {
        int row = R0 + wr * 64 + mi * 16 + lg * 4 + r;
        out[(size_t)row * 1024 + col] = acc[mi][ni][r] + badd;
      }
    }
  }
}

// ---------- launcher ----------
extern "C" void kernel_launch(void* const* d_in, const int* in_sizes, int n_in,
                              void* d_out, int out_size, void* d_ws, size_t ws_size,
                              hipStream_t stream) {
  const float* x  = (const float*)d_in[0];
  const float* wq = (const float*)d_in[1];
  const float* bq = (const float*)d_in[2];
  const float* wk = (const float*)d_in[3];
  const float* bk = (const float*)d_in[4];
  const float* wv = (const float*)d_in[5];
  const float* bv = (const float*)d_in[6];
  const float* wo = (const float*)d_in[7];
  const float* bo = (const float*)d_in[8];
  float* out = (float*)d_out;

  char* ws = (char*)d_ws;
  u16* xb  = (u16*)(ws + ((size_t)0 << 20));   // [4096][1024] bf16      8 MB
  u16* wbt = (u16*)(ws + ((size_t)8 << 20));   // [3072][1024] bf16      6 MB
  u16* wot = (u16*)(ws + ((size_t)14 << 20));  // [1024][1024] bf16      2 MB
  u16* qb  = (u16*)(ws + ((size_t)16 << 20));  // [32][2048][64] bf16    8 MB
  u16* kbf = (u16*)(ws + ((size_t)24 << 20));  // [32][2048][64] bf16    8 MB
  u16* vtb = (u16*)(ws + ((size_t)32 << 20));  // [32][32][64][64] bf16  8 MB
  u16* zb  = (u16*)(ws + ((size_t)40 << 20));  // [4096][1024] bf16      8 MB

  prep_all<<<dim3(5120), dim3(256), 0, stream>>>(x, wq, wk, wv, wo, xb, wbt, wot);
  gemm_qkv<<<dim3(32 * 24), dim3(256), 0, stream>>>(xb, wbt, bq, bk, bv, qb, kbf, vtb);
  attn_kern<<<dim3(1056), dim3(256), 0, stream>>>(qb, kbf, vtb, zb);  // + fused mean_v
  gemm_out<<<dim3(32 * 16), dim3(256), 0, stream>>>(zb, wot, bo, out);
}

// Round 19
// 107.285 us; speedup vs baseline: 1.0090x; 1.0090x over previous
//
#include <hip/hip_runtime.h>

typedef __attribute__((ext_vector_type(8))) __bf16 bf16x8;
typedef __attribute__((ext_vector_type(4))) float  f32x4;
typedef unsigned short u16;
typedef unsigned int   u32;

// ---------- helpers ----------
__device__ __forceinline__ u16 f2b(float f) {           // f32 -> bf16 (RNE)
  u32 u = __builtin_bit_cast(u32, f);
  u32 r = (u + 0x7FFFu + ((u >> 16) & 1u)) >> 16;
  return (u16)r;
}

typedef __attribute__((address_space(3))) void lds_void;
typedef const __attribute__((address_space(1))) void gbl_void;

__device__ __forceinline__ void gload_lds16(const u16* g, u16* l) {
  __builtin_amdgcn_global_load_lds((gbl_void*)g, (lds_void*)l, 16, 0, 0);
}

#define QSCALE 0.18033688011112042f  /* log2(e)/8 : exp2-domain score scale */
#define MFIX   4.328085122666891f    /* 3*log2(e) : fixed softmax max (exp2 dom) */

// ---------- fused prep: x cast + weight transposes (one launch) ----------
__global__ __launch_bounds__(256) void prep_all(const float* __restrict__ x,
                                                const float* __restrict__ wq,
                                                const float* __restrict__ wk,
                                                const float* __restrict__ wv,
                                                const float* __restrict__ wo,
                                                u16* __restrict__ xb,
                                                u16* __restrict__ wbt,
                                                u16* __restrict__ wot) {
  int bid = blockIdx.x;
  int tid = threadIdx.x;
  if (bid < 4096) {
    int i = bid * 256 + tid;
    float4 v = ((const float4*)x)[i];
    ushort4 o;
    o.x = f2b(v.x); o.y = f2b(v.y); o.z = f2b(v.z); o.w = f2b(v.w);
    ((ushort4*)xb)[i] = o;
    return;
  }
  __shared__ float t[64][65];
  int sub = bid - 4096;
  const float* src; u16* dst; int sstride, dstride, r0, c0;
  if (sub < 768) {
    int proj = sub >> 8, rem = sub & 255;
    int ym = rem >> 4, xt = rem & 15;
    src = ((proj == 0) ? wq : (proj == 1) ? wk : wv) + (size_t)ym * 65536;
    dst = wbt + ((size_t)proj << 20) + (size_t)ym * 65536;
    sstride = 64; dstride = 1024; r0 = xt * 64; c0 = 0;
  } else {
    int s2 = sub - 768;
    src = wo; dst = wot;
    sstride = 1024; dstride = 1024;
    r0 = (s2 & 15) * 64; c0 = (s2 >> 4) * 64;
  }
  int rr = tid >> 2, q = tid & 3;
#pragma unroll
  for (int i = 0; i < 4; ++i) {
    float4 v = *(const float4*)&src[(size_t)(r0 + rr) * sstride + c0 + q * 16 + i * 4];
    t[rr][q * 16 + i * 4 + 0] = v.x;
    t[rr][q * 16 + i * 4 + 1] = v.y;
    t[rr][q * 16 + i * 4 + 2] = v.z;
    t[rr][q * 16 + i * 4 + 3] = v.w;
  }
  __syncthreads();
  int cc = rr;
#pragma unroll
  for (int i = 0; i < 4; ++i) {
    ushort4 o;
    o.x = f2b(t[q * 16 + i * 4 + 0][cc]);
    o.y = f2b(t[q * 16 + i * 4 + 1][cc]);
    o.z = f2b(t[q * 16 + i * 4 + 2][cc]);
    o.w = f2b(t[q * 16 + i * 4 + 3][cc]);
    *(ushort4*)&dst[(size_t)(c0 + cc) * dstride + r0 + q * 16 + i * 4] = o;
  }
}

// ---------- shared GEMM mainloop: 128x128 tile, BK=32, 4 waves (r4/r7 form) ----------
template <int KDIM>
__device__ __forceinline__ void gemm_main(const u16* __restrict__ A,
                                          const u16* __restrict__ Bm,
                                          int R0, int C0,
                                          u16* As, u16* Bs, f32x4 (&acc)[4][4]) {
  int tid = threadIdx.x;
  int w = tid >> 6, l = tid & 63;
  int lr = l & 15, lg = l >> 4;
  int wr = w >> 1, wc = w & 1;
  for (int k0 = 0; k0 < KDIM; k0 += 32) {
#pragma unroll
    for (int i = 0; i < 2; ++i) {
      int t = w * 2 + i;
      gload_lds16(A  + (size_t)(R0 + t * 16 + (l >> 2)) * KDIM + k0 + (l & 3) * 8, &As[t * 512]);
      gload_lds16(Bm + (size_t)(C0 + t * 16 + (l >> 2)) * KDIM + k0 + (l & 3) * 8, &Bs[t * 512]);
    }
    __syncthreads();
    bf16x8 af[4], bfr[4];
#pragma unroll
    for (int mi = 0; mi < 4; ++mi)
      af[mi] = *(const bf16x8*)&As[(wr * 64 + mi * 16 + lr) * 32 + lg * 8];
#pragma unroll
    for (int ni = 0; ni < 4; ++ni)
      bfr[ni] = *(const bf16x8*)&Bs[(wc * 64 + ni * 16 + lr) * 32 + lg * 8];
#pragma unroll
    for (int mi = 0; mi < 4; ++mi)
#pragma unroll
      for (int ni = 0; ni < 4; ++ni)
        acc[mi][ni] = __builtin_amdgcn_mfma_f32_16x16x32_bf16(af[mi], bfr[ni], acc[mi][ni], 0, 0, 0);
    __syncthreads();
  }
}

// ---------- GEMM1: Y = x @ [Wq|Wk|Wv] ; 128x128, grid 768, direct scatter (r7/r8) ----------
__global__ __launch_bounds__(256) void gemm_qkv(const u16* __restrict__ xb,
                                                const u16* __restrict__ wbt,
                                                const float* __restrict__ bq,
                                                const float* __restrict__ bk,
                                                const float* __restrict__ bv,
                                                u16* __restrict__ qb,
                                                u16* __restrict__ kbf,
                                                u16* __restrict__ vtb) {
  __shared__ __align__(16) u16 As[128 * 32];
  __shared__ __align__(16) u16 Bs[128 * 32];
  f32x4 acc[4][4];
#pragma unroll
  for (int mi = 0; mi < 4; ++mi)
#pragma unroll
    for (int ni = 0; ni < 4; ++ni) acc[mi][ni] = (f32x4){0.f, 0.f, 0.f, 0.f};

  int bid = blockIdx.x;
  int rt = bid & 31, ct = bid >> 5;   // 32 row tiles x 24 col tiles
  int R0 = rt * 128, C0 = ct * 128;
  gemm_main<1024>(xb, wbt, R0, C0, As, Bs, acc);

  int tid = threadIdx.x;
  int w = tid >> 6, l = tid & 63;
  int lr = l & 15, lg = l >> 4;
  int wr = w >> 1, wc = w & 1;
#pragma unroll
  for (int ni = 0; ni < 4; ++ni) {
    int col = C0 + wc * 64 + ni * 16 + lr;
    int proj = col >> 10;            // uniform per block
    int within = col & 1023;
    int n = within >> 6, h = within & 63;
    const float* bias = (proj == 0) ? bq : (proj == 1 ? bk : bv);
    float badd = bias[within];
    float scl = (proj == 0) ? QSCALE : 1.0f;   // fold score scale+log2e into Q
#pragma unroll
    for (int mi = 0; mi < 4; ++mi) {
#pragma unroll
      for (int r = 0; r < 4; ++r) {
        int row = R0 + wr * 64 + mi * 16 + lg * 4 + r;
        int b = row >> 11, p = row & 2047;
        int bn = b * 16 + n;
        u16 u = f2b((acc[mi][ni][r] + badd) * scl);
        if (proj == 0)      qb [((size_t)bn * 2048 + p) * 64 + h] = u;
        else if (proj == 1) kbf[((size_t)bn * 2048 + p) * 64 + h] = u;
        else                vtb[(((size_t)bn * 32 + (p >> 6)) * 64 + h) * 64 + (p & 63)] = u;
      }
    }
  }
}

// ---------- flash attention (inverted-causal mask: keep pk > pq) ----------
// 1056 blocks: 0..1023 = (32 bn x 32 chunks, LPT); 1024..1055 = fused mean_v
// (row-2047 output: uniform softmax -> mean(V); attn path skips that row).
// 4 waves/block; LDS 40KB -> 4 blocks/CU. 2-buffer K/V staging, depth-1
// prefetch with counted vmcnt(4), raw barriers. Fixed-max softmax (exp2).
#define ATTN_STEP(BUFC, MASKED)                                                \
  {                                                                            \
    if (t + 1 < trips) {                                                       \
      gload_lds16(sk,       &Ks[BUFC ^ 1][w * 1024]);                          \
      gload_lds16(sk + 512, &Ks[BUFC ^ 1][w * 1024 + 512]);                    \
      gload_lds16(sv,       &Vs[BUFC ^ 1][w * 1024]);                          \
      gload_lds16(sv + 512, &Vs[BUFC ^ 1][w * 1024 + 512]);                    \
      sk += 4096; sv += 4096;                                                  \
      asm volatile("s_waitcnt vmcnt(4)" ::: "memory");                         \
    } else {                                                                   \
      asm volatile("s_waitcnt vmcnt(0)" ::: "memory");                         \
    }                                                                          \
    __builtin_amdgcn_s_barrier();                                              \
    asm volatile("" ::: "memory");                                             \
    f32x4 sacc[4];                                                             \
    __builtin_amdgcn_s_setprio(1);                                             \
    _Pragma("unroll") for (int nb = 0; nb < 4; ++nb) {                         \
      int row = nb * 16 + lr, sw = row & 7;                                    \
      bf16x8 kf0 = *(const bf16x8*)&Ks[BUFC][row * 64 + ((lg ^ sw) << 3)];     \
      bf16x8 kf1 = *(const bf16x8*)&Ks[BUFC][row * 64 + (((lg + 4) ^ sw) << 3)]; \
      f32x4 s = (f32x4){0.f, 0.f, 0.f, 0.f};                                   \
      s = __builtin_amdgcn_mfma_f32_16x16x32_bf16(qf0, kf0, s, 0, 0, 0);       \
      s = __builtin_amdgcn_mfma_f32_16x16x32_bf16(qf1, kf1, s, 0, 0, 0);       \
      sacc[nb] = s;                                                            \
    }                                                                          \
    __builtin_amdgcn_s_setprio(0);                                             \
    u16 pbv[4][4];                                                             \
    if (MASKED) {                                                              \
      _Pragma("unroll") for (int nb = 0; nb < 4; ++nb) {                       \
        int key = nb * 16 + lr;                                                \
        _Pragma("unroll") for (int r = 0; r < 4; ++r) {                        \
          int qrow = w * 16 + lg * 4 + r;                                      \
          float xv = (key > qrow) ? sacc[nb][r] : -1.0e10f;                    \
          float pe = __builtin_amdgcn_exp2f(xv - MFIX);                        \
          rsum[r] += pe;                                                       \
          pbv[nb][r] = __builtin_bit_cast(u16, (__bf16)pe);                    \
        }                                                                      \
      }                                                                        \
    } else {                                                                   \
      _Pragma("unroll") for (int nb = 0; nb < 4; ++nb)                         \
        _Pragma("unroll") for (int r = 0; r < 4; ++r) {                        \
          float pe = __builtin_amdgcn_exp2f(sacc[nb][r] - MFIX);               \
          rsum[r] += pe;                                                       \
          pbv[nb][r] = __builtin_bit_cast(u16, (__bf16)pe);                    \
        }                                                                      \
    }                                                                          \
    _Pragma("unroll") for (int nb = 0; nb < 4; ++nb)                           \
      _Pragma("unroll") for (int r = 0; r < 4; ++r) {                          \
        int prow = lg * 4 + r;                                                 \
        Plds[w][prow * 64 + ((((nb * 2) + (lr >> 3)) ^ (prow & 7)) << 3) + (lr & 7)] = pbv[nb][r]; \
      }                                                                        \
    asm volatile("s_waitcnt lgkmcnt(0)" ::: "memory");                         \
    __builtin_amdgcn_sched_barrier(0);                                         \
    bf16x8 pf0 = *(const bf16x8*)&Plds[w][lr * 64 + ((lg ^ (lr & 7)) << 3)];   \
    bf16x8 pf1 = *(const bf16x8*)&Plds[w][lr * 64 + (((4 + lg) ^ (lr & 7)) << 3)]; \
    __builtin_amdgcn_s_setprio(1);                                             \
    _Pragma("unroll") for (int hb = 0; hb < 4; ++hb) {                         \
      int row = hb * 16 + lr, sw = row & 7;                                    \
      bf16x8 vf0 = *(const bf16x8*)&Vs[BUFC][row * 64 + ((lg ^ sw) << 3)];     \
      bf16x8 vf1 = *(const bf16x8*)&Vs[BUFC][row * 64 + (((lg + 4) ^ sw) << 3)]; \
      oacc[hb] = __builtin_amdgcn_mfma_f32_16x16x32_bf16(pf0, vf0, oacc[hb], 0, 0, 0); \
      oacc[hb] = __builtin_amdgcn_mfma_f32_16x16x32_bf16(pf1, vf1, oacc[hb], 0, 0, 0); \
    }                                                                          \
    __builtin_amdgcn_s_setprio(0);                                             \
    asm volatile("" ::: "memory");                                             \
    __builtin_amdgcn_s_barrier();                                              \
    ++t;                                                                       \
  }

__global__ __launch_bounds__(256, 4) void attn_kern(const u16* __restrict__ qb,
                                                    const u16* __restrict__ kbf,
                                                    const u16* __restrict__ vtb,
                                                    u16* __restrict__ zb) {
  __shared__ __align__(16) u16 Ks[2][4096];   // 16 KB
  __shared__ __align__(16) u16 Vs[2][4096];   // 16 KB
  __shared__ __align__(16) u16 Plds[4][1024]; // 8 KB, XOR-swizzled [16][64]/wave

  int bid = blockIdx.x;
  int tid = threadIdx.x;

  if (bid >= 1024) {
    // ---- fused mean_v: row-2047 output = mean over V rows (uniform softmax) ----
    float* red = (float*)&Ks[0][0];          // alias 1 KB of the staging pool
    int bn = bid - 1024;
    int w = tid >> 6, h = tid & 63;
    const u16* base = vtb + (size_t)bn * 131072 + (size_t)h * 64;
    float acc = 0.f;
    for (int pb = w; pb < 32; pb += 4) {
      const u16* r = base + (size_t)pb * 4096;
#pragma unroll
      for (int c = 0; c < 8; ++c) {
        bf16x8 v = *(const bf16x8*)(r + c * 8);
#pragma unroll
        for (int j = 0; j < 8; ++j) acc += (float)v[j];
      }
    }
    red[w * 64 + h] = acc;
    __syncthreads();
    if (w == 0) {
      float s = (red[h] + red[64 + h] + red[128 + h] + red[192 + h]) * (1.0f / 2048.0f);
      int b = bn >> 4, n = bn & 15;
      zb[((size_t)(b * 2048 + 2047) * 16 + n) * 64 + h] = f2b(s);
    }
    return;
  }

  int bn = bid & 31, c = bid >> 5;        // c ascending = longest-first (LPT)
  int trips = 32 - c;                     // k-tiles c..31
  int w = tid >> 6, l = tid & 63;
  int lr = l & 15, lg = l >> 4;

  const u16* Q  = qb  + (size_t)bn * 131072;
  const u16* Kp = kbf + (size_t)bn * 131072;
  const u16* Vt = vtb + (size_t)bn * 131072;

  // staging source offset with inverse XOR-swizzle (LDS dest stays linear)
  int row0 = w * 16 + (l >> 3), col8 = l & 7;
  int soff = row0 * 64 + ((col8 ^ (row0 & 7)) << 3);

  int q0w = c * 64 + w * 16;
  bf16x8 qf0 = *(const bf16x8*)&Q[(size_t)(q0w + lr) * 64 + lg * 8];
  bf16x8 qf1 = *(const bf16x8*)&Q[(size_t)(q0w + lr) * 64 + 32 + lg * 8];

  float rsum[4];
  f32x4 oacc[4];
#pragma unroll
  for (int r = 0; r < 4; ++r) rsum[r] = 0.0f;
#pragma unroll
  for (int hb = 0; hb < 4; ++hb) oacc[hb] = (f32x4){0.f, 0.f, 0.f, 0.f};

  // prologue: stage tile 0 into buf 0
  const u16* sk = Kp + (size_t)c * 4096 + soff;
  const u16* sv = Vt + (size_t)c * 4096 + soff;
  gload_lds16(sk,       &Ks[0][w * 1024]);
  gload_lds16(sk + 512, &Ks[0][w * 1024 + 512]);
  gload_lds16(sv,       &Vs[0][w * 1024]);
  gload_lds16(sv + 512, &Vs[0][w * 1024 + 512]);
  sk += 4096; sv += 4096;

  int t = 0;
  ATTN_STEP(0, true)                       // t=0: masked tile
  while (t + 1 < trips) {
    ATTN_STEP(1, false)
    ATTN_STEP(0, false)
  }
  if (t < trips) ATTN_STEP(1, false)       // tail (trips even)

  // ---- final row-sum reduce + store (skip row 2047: owned by mean_v blocks) ----
#pragma unroll
  for (int r = 0; r < 4; ++r) {
    float v = rsum[r];
    v += __shfl_xor(v, 1);
    v += __shfl_xor(v, 2);
    v += __shfl_xor(v, 4);
    v += __shfl_xor(v, 8);
    rsum[r] = 1.0f / v;
  }
  int b = bn >> 4, n = bn & 15;
#pragma unroll
  for (int hb = 0; hb < 4; ++hb) {
    int h = hb * 16 + lr;
#pragma unroll
    for (int r = 0; r < 4; ++r) {
      int qrow = q0w + lg * 4 + r;
      if (qrow != 2047)
        zb[((size_t)(b * 2048 + qrow) * 16 + n) * 64 + h] = f2b(oacc[hb][r] * rsum[r]);
    }
  }
}

// ---------- GEMM2: out = z @ Wo + bias_out (f32 out) ----------
// 128x64 tiles -> 512 blocks (2/CU) + XCD swizzle (r17 best-measured form).
__global__ __launch_bounds__(256) void gemm_out(const u16* __restrict__ zb,
                                                const u16* __restrict__ wot,
                                                const float* __restrict__ bo,
                                                float* __restrict__ out) {
  __shared__ __align__(16) u16 As[128 * 32];  // 8 KB
  __shared__ __align__(16) u16 Bs[64 * 32];   // 4 KB
  f32x4 acc[4][2];
#pragma unroll
  for (int mi = 0; mi < 4; ++mi)
#pragma unroll
    for (int ni = 0; ni < 2; ++ni) acc[mi][ni] = (f32x4){0.f, 0.f, 0.f, 0.f};

  int bid = (blockIdx.x & 7) * 64 + (blockIdx.x >> 3);
  int rt = bid >> 4, ct = bid & 15;   // 32 row tiles x 16 col tiles
  int R0 = rt * 128, C0 = ct * 64;

  int tid = threadIdx.x;
  int w = tid >> 6, l = tid & 63;
  int lr = l & 15, lg = l >> 4;
  int wr = w >> 1, wc = w & 1;

  for (int k0 = 0; k0 < 1024; k0 += 32) {
#pragma unroll
    for (int i = 0; i < 2; ++i) {
      int t = w * 2 + i;
      gload_lds16(zb + (size_t)(R0 + t * 16 + (l >> 2)) * 1024 + k0 + (l & 3) * 8, &As[t * 512]);
    }
    gload_lds16(wot + (size_t)(C0 + w * 16 + (l >> 2)) * 1024 + k0 + (l & 3) * 8, &Bs[w * 512]);
    __syncthreads();
    bf16x8 af[4], bfr[2];
#pragma unroll
    for (int mi = 0; mi < 4; ++mi)
      af[mi] = *(const bf16x8*)&As[(wr * 64 + mi * 16 + lr) * 32 + lg * 8];
#pragma unroll
    for (int ni = 0; ni < 2; ++ni)
      bfr[ni] = *(const bf16x8*)&Bs[(wc * 32 + ni * 16 + lr) * 32 + lg * 8];
#pragma unroll
    for (int mi = 0; mi < 4; ++mi)
#pragma unroll
      for (int ni = 0; ni < 2; ++ni)
        acc[mi][ni] = __builtin_amdgcn_mfma_f32_16x16x32_bf16(af[mi], bfr[ni], acc[mi][ni], 0, 0, 0);
    __syncthreads();
  }

#pragma unroll
  for (int ni = 0; ni < 2; ++ni) {
    int col = C0 + wc * 32 + ni * 16 + lr;
    float badd = bo[col];
#pragma unroll
    for (int mi = 0; mi < 4; ++mi) {
#pragma unroll
      for (int r = 0; r < 4; ++r) {
        int row = R0 + wr * 64 + mi * 16 + lg * 4 + r;
        out[(size_t)row * 1024 + col] = acc[mi][ni][r] + badd;
      }
    }
  }
}

// ---------- launcher ----------
extern "C" void kernel_launch(void* const* d_in, const int* in_sizes, int n_in,
                              void* d_out, int out_size, void* d_ws, size_t ws_size,
                              hipStream_t stream) {
  const float* x  = (const float*)d_in[0];
  const float* wq = (const float*)d_in[1];
  const float* bq = (const float*)d_in[2];
  const float* wk = (const float*)d_in[3];
  const float* bk = (const float*)d_in[4];
  const float* wv = (const float*)d_in[5];
  const float* bv = (const float*)d_in[6];
  const float* wo = (const float*)d_in[7];
  const float* bo = (const float*)d_in[8];
  float* out = (float*)d_out;

  char* ws = (char*)d_ws;
  u16* xb  = (u16*)(ws + ((size_t)0 << 20));   // [4096][1024] bf16      8 MB
  u16* wbt = (u16*)(ws + ((size_t)8 << 20));   // [3072][1024] bf16      6 MB
  u16* wot = (u16*)(ws + ((size_t)14 << 20));  // [1024][1024] bf16      2 MB
  u16* qb  = (u16*)(ws + ((size_t)16 << 20));  // [32][2048][64] bf16    8 MB
  u16* kbf = (u16*)(ws + ((size_t)24 << 20));  // [32][2048][64] bf16    8 MB
  u16* vtb = (u16*)(ws + ((size_t)32 << 20));  // [32][32][64][64] bf16  8 MB
  u16* zb  = (u16*)(ws + ((size_t)40 << 20));  // [4096][1024] bf16      8 MB

  prep_all<<<dim3(5120), dim3(256), 0, stream>>>(x, wq, wk, wv, wo, xb, wbt, wot);
  gemm_qkv<<<dim3(32 * 24), dim3(256), 0, stream>>>(xb, wbt, bq, bk, bv, qb, kbf, vtb);
  attn_kern<<<dim3(1056), dim3(256), 0, stream>>>(qb, kbf, vtb, zb);  // + fused mean_v
  gemm_out<<<dim3(32 * 16), dim3(256), 0, stream>>>(zb, wot, bo, out);
}